// Round 2
// baseline (493.643 us; speedup 1.0000x reference)
//
#include <hip/hip_runtime.h>
#include <hip/hip_fp16.h>

// GCN 2-layer forward. R1: multi-block scan. R2: fp16 intermediates.
// R3: wide-gather aggregation. R4: packed hist atomic + fp16 MFMA GEMMs.
// R5: reformulated normalization, packed 8B edges, self-loops in scan.
// R6: bucket-sort CSR build. R7: LDS-free fragment-ordered GEMM.
// R8: GEMM latency fix — full K-strip register prefetch + 16 rows/wave.
// R9: scatter latency fix — 2048 edges/block, int4 loads, ranks in registers.
// R10: agg1 L2-locality fix — agg1 was 64 µs: random 256B gathers over a
//      25.6MB working set miss the 4MB/XCD L2s. h' now lives in blocked
//      layout [8 chunks][N][16 feat]; agg blocks take chunk = bid&7 so (with
//      the %8 round-robin block->XCD mapping) each XCD gathers only its own
//      3.2MB chunk -> L2-resident. Edges re-streamed 8x (sequential, L3-hit).
//      GEMM1 writes blocked C; GEMM2 reads blocked A (coalescing preserved).

#define BLK 256
#define NPB 128          // nodes per bucket (dstlocal = dst & 127)
#define MAXBUCK 1024
#define FCAP 3072        // bucket_final LDS edge capacity
#define SCHUNK 2048      // edges per scatter block (8 per thread)

typedef _Float16 half8 __attribute__((ext_vector_type(8)));
typedef float f32x4 __attribute__((ext_vector_type(4)));

// --- 1. bucket histogram (fire-and-forget atomics, LDS-privatized) ---
__global__ __launch_bounds__(256) void bucket_hist_kernel(const int* __restrict__ dst, int E,
                                                          int nbuck, int* __restrict__ bhist) {
    __shared__ int lh[MAXBUCK];
    for (int i = threadIdx.x; i < nbuck; i += 256) lh[i] = 0;
    __syncthreads();
    if ((E & 3) == 0) {
        int E4 = E >> 2;
        for (int i = blockIdx.x * 256 + threadIdx.x; i < E4; i += gridDim.x * 256) {
            int4 dv = *(const int4*)(dst + i * 4);
            atomicAdd(&lh[dv.x >> 7], 1);
            atomicAdd(&lh[dv.y >> 7], 1);
            atomicAdd(&lh[dv.z >> 7], 1);
            atomicAdd(&lh[dv.w >> 7], 1);
        }
    } else {
        for (int e = blockIdx.x * 256 + threadIdx.x; e < E; e += gridDim.x * 256)
            atomicAdd(&lh[dst[e] >> 7], 1);
    }
    __syncthreads();
    for (int i = threadIdx.x; i < nbuck; i += 256)
        if (lh[i]) atomicAdd(&bhist[i], lh[i]);
}

// --- 2. dual exclusive scan over buckets ---
__global__ __launch_bounds__(256) void bucket_scan_kernel(const int* __restrict__ bhist,
                                                          int nbuck, int N,
                                                          int* __restrict__ ebBase,
                                                          int* __restrict__ bcursor,
                                                          int* __restrict__ outBase,
                                                          int* __restrict__ row_ptr) {
    __shared__ int sA[256], sB[256];
    int tid = threadIdx.x;
    int v1[4], v2[4];
    int s1 = 0, s2 = 0;
    #pragma unroll
    for (int j = 0; j < 4; j++) {
        int idx = tid * 4 + j;
        int h = (idx < nbuck) ? bhist[idx] : 0;
        int nodes = 0;
        if (idx < nbuck) {
            nodes = N - idx * NPB;
            nodes = nodes > NPB ? NPB : nodes;
            if (nodes < 0) nodes = 0;
        }
        v1[j] = h; v2[j] = h + nodes;
        s1 += v1[j]; s2 += v2[j];
    }
    sA[tid] = s1; sB[tid] = s2;
    __syncthreads();
    for (int off = 1; off < 256; off <<= 1) {
        int a = (tid >= off) ? sA[tid - off] : 0;
        int b = (tid >= off) ? sB[tid - off] : 0;
        __syncthreads();
        sA[tid] += a; sB[tid] += b;
        __syncthreads();
    }
    int run1 = sA[tid] - s1, run2 = sB[tid] - s2;
    #pragma unroll
    for (int j = 0; j < 4; j++) {
        int idx = tid * 4 + j;
        if (idx < nbuck) {
            ebBase[idx] = run1; bcursor[idx] = run1; outBase[idx] = run2;
        }
        run1 += v1[j]; run2 += v2[j];
    }
    if (tid == 255) { ebBase[nbuck] = run1; row_ptr[N] = run2; }
}

// --- 3. scatter edges into bucket-grouped edgesB ---
__global__ __launch_bounds__(256) void bucket_scatter_kernel(const int* __restrict__ src,
                                                             const int* __restrict__ dst,
                                                             const float* __restrict__ ew,
                                                             int* __restrict__ bcursor,
                                                             uint2* __restrict__ edgesB,
                                                             int E, int nbuck) {
    __shared__ int lh[MAXBUCK];
    __shared__ int lbase[MAXBUCK];
    const int tid = threadIdx.x;
    for (int i = tid; i < nbuck; i += 256) lh[i] = 0;
    __syncthreads();
    const int beg = blockIdx.x * SCHUNK;
    const bool vec = ((E & 3) == 0);
    int d[2][4], rk[2][4];
    #pragma unroll
    for (int j = 0; j < 2; j++) {
        int e = beg + j * 1024 + tid * 4;
        if (vec && e + 3 < E) {
            int4 dv = *(const int4*)(dst + e);
            d[j][0] = dv.x; d[j][1] = dv.y; d[j][2] = dv.z; d[j][3] = dv.w;
            #pragma unroll
            for (int k = 0; k < 4; k++) rk[j][k] = atomicAdd(&lh[d[j][k] >> 7], 1);
        } else {
            #pragma unroll
            for (int k = 0; k < 4; k++) {
                if (e + k < E) {
                    d[j][k] = dst[e + k];
                    rk[j][k] = atomicAdd(&lh[d[j][k] >> 7], 1);
                } else {
                    d[j][k] = -1;
                }
            }
        }
    }
    __syncthreads();
    for (int i = tid; i < nbuck; i += 256) {
        int c = lh[i];
        lbase[i] = c ? atomicAdd(&bcursor[i], c) : 0;
    }
    __syncthreads();
    #pragma unroll
    for (int j = 0; j < 2; j++) {
        int e = beg + j * 1024 + tid * 4;
        if (vec && e + 3 < E) {
            int4 sv = *(const int4*)(src + e);
            float4 wv = *(const float4*)(ew + e);
            int sa[4] = {sv.x, sv.y, sv.z, sv.w};
            float wa[4] = {wv.x, wv.y, wv.z, wv.w};
            #pragma unroll
            for (int k = 0; k < 4; k++) {
                int b = d[j][k] >> 7;
                edgesB[lbase[b] + rk[j][k]] =
                    make_uint2((unsigned)sa[k] | ((unsigned)(d[j][k] & 127) << 17),
                               __float_as_uint(wa[k]));
            }
        } else {
            #pragma unroll
            for (int k = 0; k < 4; k++) {
                if (d[j][k] >= 0) {
                    int b = d[j][k] >> 7;
                    edgesB[lbase[b] + rk[j][k]] =
                        make_uint2((unsigned)src[e + k] | ((unsigned)(d[j][k] & 127) << 17),
                                   __float_as_uint(ew[e + k]));
                }
            }
        }
    }
}

// --- 4. per-bucket finalize ---
__global__ __launch_bounds__(256) void bucket_final_kernel(const uint2* __restrict__ edgesB,
                                                           const int* __restrict__ ebBase,
                                                           const int* __restrict__ outBase,
                                                           int* __restrict__ row_ptr,
                                                           float* __restrict__ dinv,
                                                           uint2* __restrict__ edges,
                                                           int N, int nbuck) {
    __shared__ uint2 eb[FCAP];
    __shared__ int cnts[NPB];
    __shared__ float wsum[NPB];
    __shared__ int starts[NPB];
    int b = blockIdx.x;
    int tid = threadIdx.x;
    int beg = ebBase[b];
    int cnt = ebBase[b + 1] - beg;
    if (cnt > FCAP) cnt = FCAP;
    int node0 = b * NPB;
    int nn = N - node0; if (nn > NPB) nn = NPB;
    for (int i = tid; i < nn; i += 256) { cnts[i] = 0; wsum[i] = 0.f; }
    for (int i = tid; i < cnt; i += 256) eb[i] = edgesB[beg + i];
    __syncthreads();
    for (int i = tid; i < cnt; i += 256) {
        int dl = eb[i].x >> 17;
        atomicAdd(&cnts[dl], 1);
        atomicAdd(&wsum[dl], __uint_as_float(eb[i].y));
    }
    __syncthreads();
    if (tid < 64) {
        int i0 = 2 * tid, i1 = 2 * tid + 1;
        int c0 = (i0 < nn) ? cnts[i0] + 1 : 0;
        int c1 = (i1 < nn) ? cnts[i1] + 1 : 0;
        int s = c0 + c1;
        int incl = s;
        #pragma unroll
        for (int off = 1; off < 64; off <<= 1) {
            int t = __shfl_up(incl, off);
            if (tid >= off) incl += t;
        }
        int excl = incl - s;
        int outB = outBase[b];
        if (i0 < nn) starts[i0] = outB + excl;
        if (i1 < nn) starts[i1] = outB + excl + c0;
    }
    __syncthreads();
    for (int i = tid; i < nn; i += 256) {
        int rp = starts[i];
        int node = node0 + i;
        row_ptr[node] = rp;
        dinv[node] = rsqrtf(wsum[i] + 1.0f);
        edges[rp] = make_uint2((unsigned)node, __float_as_uint(1.0f));
        cnts[i] = 1;
    }
    __syncthreads();
    for (int i = tid; i < cnt; i += 256) {
        int dl = eb[i].x >> 17;
        int r = atomicAdd(&cnts[dl], 1);
        edges[starts[dl] + r] = make_uint2(eb[i].x & 0x1FFFFu, eb[i].y);
    }
}

// W[K][NN] fp32 -> Bord fragment order: Bord[((t*KS+ks)*64+lane)*8+j]
//   = W[ks*32+(lane>>4)*8+j][t*16+(lane&15)]
template<int K, int NT>
__global__ void convert_bord_kernel(const float* __restrict__ W, _Float16* __restrict__ Bord) {
    constexpr int NN = NT * 16;
    constexpr int KS = K / 32;
    int i = blockIdx.x * blockDim.x + threadIdx.x;
    if (i < NT * KS * 64 * 8) {
        int j = i & 7;
        int lane = (i >> 3) & 63;
        int ks = (i >> 9) % KS;
        int t = i / (KS * 512);
        int kk = ks * 32 + (lane >> 4) * 8 + j;
        int nnj = t * 16 + (lane & 15);
        Bord[i] = (_Float16)W[(size_t)kk * NN + nnj];
    }
}

// LDS-free MFMA GEMM, full K-strip register prefetch. One wave owns 16 rows.
// C[M,NN] = scale[m]*(A[M,K] @ B), B pre-shuffled to fragment order.
// BIN: A is feature-chunk-blocked [K/16][M][16] (fp16 path only).
// BOUT: C written feature-chunk-blocked [NT][M][16].
template<int K, int NT, int MINW, typename AT, bool BIN, bool BOUT>
__global__ __launch_bounds__(256, MINW) void gemm_mfma_kernel(const AT* __restrict__ A,
                                                              const _Float16* __restrict__ Bord,
                                                              const float* __restrict__ scale,
                                                              _Float16* __restrict__ C, int M) {
    constexpr int NN = NT * 16;
    constexpr int KS = K / 32;
    const int wave_id = (blockIdx.x * blockDim.x + threadIdx.x) >> 6;
    const int lane = threadIdx.x & 63;
    const int quad = lane >> 4;
    const int nl = lane & 15;
    const int row_base = wave_id * 16;
    if (row_base >= M) return;
    const int m = min(row_base + nl, M - 1);

    // ---- prefetch the whole K-strip: all loads issued before first use ----
    float4 raw[KS][2];   // fp32 source path
    half8 afr[KS];       // fp16 source path
    if constexpr (sizeof(AT) == 4) {
        const float* ap = (const float*)A + (size_t)m * K + quad * 8;
        #pragma unroll
        for (int ks = 0; ks < KS; ks++) {
            raw[ks][0] = *(const float4*)(ap + ks * 32);
            raw[ks][1] = *(const float4*)(ap + ks * 32 + 4);
        }
    } else if constexpr (BIN) {
        // blocked A: feature f = ks*32 + quad*8 lives in chunk c = f/16
        const _Float16* ap = (const _Float16*)A;
        #pragma unroll
        for (int ks = 0; ks < KS; ks++) {
            int c = 2 * ks + (quad >> 1);
            afr[ks] = *(const half8*)(ap + ((size_t)c * M + m) * 16 + (quad & 1) * 8);
        }
    } else {
        const _Float16* ap = (const _Float16*)A + (size_t)m * K + quad * 8;
        #pragma unroll
        for (int ks = 0; ks < KS; ks++)
            afr[ks] = *(const half8*)(ap + ks * 32);
    }

    f32x4 acc[NT] = {};
    #pragma unroll
    for (int ks = 0; ks < KS; ks++) {
        half8 af;
        if constexpr (sizeof(AT) == 4) {
            af[0] = (_Float16)raw[ks][0].x; af[1] = (_Float16)raw[ks][0].y;
            af[2] = (_Float16)raw[ks][0].z; af[3] = (_Float16)raw[ks][0].w;
            af[4] = (_Float16)raw[ks][1].x; af[5] = (_Float16)raw[ks][1].y;
            af[6] = (_Float16)raw[ks][1].z; af[7] = (_Float16)raw[ks][1].w;
        } else {
            af = afr[ks];
        }
        #pragma unroll
        for (int t = 0; t < NT; t++) {
            half8 bf = *(const half8*)(Bord + ((size_t)(t * KS + ks) * 64 + lane) * 8);
            acc[t] = __builtin_amdgcn_mfma_f32_16x16x32_f16(af, bf, acc[t], 0, 0, 0);
        }
    }

    #pragma unroll
    for (int r = 0; r < 4; r++) {
        int grow = row_base + quad * 4 + r;
        if (grow < M) {
            float sc = scale[grow];
            #pragma unroll
            for (int t = 0; t < NT; t++) {
                _Float16 val = (_Float16)(sc * acc[t][r]);
                if constexpr (BOUT)
                    C[((size_t)t * M + grow) * 16 + nl] = val;
                else
                    C[(size_t)grow * NN + t * 16 + nl] = val;
            }
        }
    }
}

__device__ inline void accum8(float* acc, uint4 p, float v) {
    const __half2* q = (const __half2*)&p;
    #pragma unroll
    for (int k = 0; k < 4; k++) {
        float2 f = __half22float2(q[k]);
        acc[2 * k]     += v * f.x;
        acc[2 * k + 1] += v * f.y;
    }
}

// Layer-1 aggregation, feature-chunked & XCD-affine.
// h blocked [8][n][16] fp16. chunk = bid&7 -> all blocks of chunk c land on
// XCD c (round-robin dispatch) -> 3.2MB gather set is L2-resident.
// Wave: 2 nodes (lane>>5), 16 edge-slots each, 2 lanes/edge (16B uint4 gather).
__global__ __launch_bounds__(256) void agg1c_kernel(const __half* __restrict__ hball,
                                                    const int* __restrict__ row_ptr,
                                                    const uint2* __restrict__ edges,
                                                    const float* __restrict__ dinv,
                                                    const float* __restrict__ b1,
                                                    __half* __restrict__ outb, int n) {
    const int c = blockIdx.x & 7;
    const int range = blockIdx.x >> 3;
    const int wave = threadIdx.x >> 6;
    const int lane = threadIdx.x & 63;
    const int sub = lane >> 5;          // which of the 2 nodes
    const int slot = (lane >> 1) & 15;  // edge slot within node
    const int hf = lane & 1;            // which 16B half of the 32B chunk row
    const __half* hc = hball + (size_t)c * n * 16;
    const float4 bA = *(const float4*)(b1 + c * 16 + hf * 8);
    const float4 bB = *(const float4*)(b1 + c * 16 + hf * 8 + 4);
    const int base = range * 128 + wave * 32 + sub;
    for (int p = 0; p < 16; p++) {
        const int node = base + p * 2;
        if (node >= n) continue;
        const int beg = row_ptr[node], end = row_ptr[node + 1];
        float acc[8] = {};
        for (int e0 = beg; e0 < end; e0 += 16) {
            int e = e0 + slot;
            int ce = min(e, end - 1);
            uint2 m = edges[ce];
            float v = (e < end) ? __uint_as_float(m.y) : 0.f;
            uint4 pk = *(const uint4*)(hc + (size_t)m.x * 16 + hf * 8);
            accum8(acc, pk, v);
        }
        #pragma unroll
        for (int j = 0; j < 8; j++) {
            acc[j] += __shfl_xor(acc[j], 2);
            acc[j] += __shfl_xor(acc[j], 4);
            acc[j] += __shfl_xor(acc[j], 8);
            acc[j] += __shfl_xor(acc[j], 16);
        }
        if (slot == 0) {
            float di = dinv[node];
            float r[8] = {di * acc[0] + bA.x, di * acc[1] + bA.y, di * acc[2] + bA.z,
                          di * acc[3] + bA.w, di * acc[4] + bB.x, di * acc[5] + bB.y,
                          di * acc[6] + bB.z, di * acc[7] + bB.w};
            #pragma unroll
            for (int j = 0; j < 8; j++) r[j] = r[j] > 0.f ? r[j] : 0.f;
            __half2 o[4];
            #pragma unroll
            for (int k = 0; k < 4; k++) o[k] = __floats2half2_rn(r[2 * k], r[2 * k + 1]);
            *(uint4*)(outb + ((size_t)c * n + node) * 16 + hf * 8) = *(uint4*)o;
        }
    }
}

// Layer-2 aggregation + log_softmax.
__global__ void agg2_kernel(const __half* __restrict__ h2, const int* __restrict__ row_ptr,
                            const uint2* __restrict__ edges, const float* __restrict__ dinv,
                            const float* __restrict__ b2, float* __restrict__ out, int n) {
    int node = blockIdx.x * (blockDim.x >> 6) + (threadIdx.x >> 6);
    int lane = threadIdx.x & 63;
    if (node >= n) return;
    int g = lane >> 3;
    int l = lane & 7;
    int beg = row_ptr[node], end = row_ptr[node + 1];
    float acc[8] = {};
    const __half* hb = h2 + l * 8;
    for (int e0 = beg; e0 < end; e0 += 16) {
        int eA = e0 + g, eB = e0 + 8 + g;
        int cA = min(eA, end - 1), cB = min(eB, end - 1);
        uint2 mA = edges[cA], mB = edges[cB];
        float vA = (eA < end) ? __uint_as_float(mA.y) : 0.f;
        float vB = (eB < end) ? __uint_as_float(mB.y) : 0.f;
        uint4 pA = *(const uint4*)(hb + (size_t)mA.x * 64);
        uint4 pB = *(const uint4*)(hb + (size_t)mB.x * 64);
        accum8(acc, pA, vA);
        accum8(acc, pB, vB);
    }
    #pragma unroll
    for (int j = 0; j < 8; j++) {
        acc[j] += __shfl_xor(acc[j], 32);
        acc[j] += __shfl_xor(acc[j], 16);
        acc[j] += __shfl_xor(acc[j], 8);
    }
    float di = dinv[node];
    float4 b0 = *(const float4*)(b2 + l * 8);
    float4 b1v = *(const float4*)(b2 + l * 8 + 4);
    acc[0] = di * acc[0] + b0.x;  acc[1] = di * acc[1] + b0.y;
    acc[2] = di * acc[2] + b0.z;  acc[3] = di * acc[3] + b0.w;
    acc[4] = di * acc[4] + b1v.x; acc[5] = di * acc[5] + b1v.y;
    acc[6] = di * acc[6] + b1v.z; acc[7] = di * acc[7] + b1v.w;
    float m = acc[0];
    #pragma unroll
    for (int j = 1; j < 8; j++) m = fmaxf(m, acc[j]);
    #pragma unroll
    for (int off = 1; off < 8; off <<= 1) m = fmaxf(m, __shfl_xor(m, off));
    float s = 0.f;
    #pragma unroll
    for (int j = 0; j < 8; j++) s += expf(acc[j] - m);
    #pragma unroll
    for (int off = 1; off < 8; off <<= 1) s += __shfl_xor(s, off);
    float ls = m + logf(s);
    if (g == 0) {
        float* op = out + (size_t)node * 64 + l * 8;
        *(float4*)(op)     = make_float4(acc[0] - ls, acc[1] - ls, acc[2] - ls, acc[3] - ls);
        *(float4*)(op + 4) = make_float4(acc[4] - ls, acc[5] - ls, acc[6] - ls, acc[7] - ls);
    }
}

extern "C" void kernel_launch(void* const* d_in, const int* in_sizes, int n_in,
                              void* d_out, int out_size, void* d_ws, size_t ws_size,
                              hipStream_t stream) {
    const float* x  = (const float*)d_in[0];
    const int*   ei = (const int*)d_in[1];
    const float* ew = (const float*)d_in[2];
    const float* W1 = (const float*)d_in[3];
    const float* b1 = (const float*)d_in[4];
    const float* W2 = (const float*)d_in[5];
    const float* b2 = (const float*)d_in[6];
    float* out = (float*)d_out;

    const int N = in_sizes[0] / 256;
    const int E = in_sizes[1] / 2;
    const int Et = E + N;
    const int* src = ei;
    const int* dst = ei + E;
    const int nbuck = (N + NPB - 1) / NPB;

    char* w = (char*)d_ws;
    size_t off = 0;
    auto carve = [&](size_t bytes) {
        void* p = w + off;
        off = (off + bytes + 255) & ~(size_t)255;
        return p;
    };
    int*      bhist   = (int*)  carve((size_t)MAXBUCK * 4);
    int*      ebBase  = (int*)  carve((size_t)(MAXBUCK + 1) * 4);
    int*      bcursor = (int*)  carve((size_t)MAXBUCK * 4);
    int*      outBase = (int*)  carve((size_t)MAXBUCK * 4);
    int*      row_ptr = (int*)  carve((size_t)(N + 1) * 4);
    float*    dinv    = (float*)carve((size_t)N * 4);
    uint2*    edgesB  = (uint2*)carve((size_t)E * 8);
    uint2*    edges   = (uint2*)carve((size_t)Et * 8);
    _Float16* bord1   = (_Float16*)carve((size_t)256 * 128 * 2);
    _Float16* bord2   = (_Float16*)carve((size_t)128 * 64 * 2);
    _Float16* bufA    = (_Float16*)carve((size_t)N * 128 * 2);  // h' blocked; later h2'
    _Float16* bufB    = (_Float16*)carve((size_t)N * 128 * 2);  // h1 blocked
    _Float16* bufC    = bufA;

    // 1. bucket-sort CSR build
    hipMemsetAsync(bhist, 0, (size_t)nbuck * 4, stream);
    bucket_hist_kernel<<<256, 256, 0, stream>>>(dst, E, nbuck, bhist);
    bucket_scan_kernel<<<1, 256, 0, stream>>>(bhist, nbuck, N, ebBase, bcursor, outBase, row_ptr);
    const int scat_blocks = (E + SCHUNK - 1) / SCHUNK;
    bucket_scatter_kernel<<<scat_blocks, 256, 0, stream>>>(src, dst, ew, bcursor, edgesB, E, nbuck);
    bucket_final_kernel<<<nbuck, 256, 0, stream>>>(edgesB, ebBase, outBase, row_ptr, dinv,
                                                   edges, N, nbuck);

    // weight reorders (tiny)
    convert_bord_kernel<256, 8><<<(256 * 128 + 255) / 256, 256, 0, stream>>>(W1, bord1);
    convert_bord_kernel<128, 4><<<(128 * 64 + 255) / 256, 256, 0, stream>>>(W2, bord2);

    // 2. Layer 1: h' = dinv * (x @ W1) [blocked], h1 = relu(dinv*agg(h')+b1) [blocked]
    const int waves = (N + 15) / 16;            // 16 rows per wave
    const int gemm_blocks = (waves + 3) / 4;    // 4 waves per block
    gemm_mfma_kernel<256, 8, 4, float, false, true><<<gemm_blocks, 256, 0, stream>>>(
        x, bord1, dinv, bufA, N);
    const int nranges = (N + 127) / 128;
    agg1c_kernel<<<nranges * 8, 256, 0, stream>>>((const __half*)bufA, row_ptr, edges, dinv, b1,
                                                  (__half*)bufB, N);

    // 3. Layer 2: h2' = dinv * (h1 @ W2) [blocked A in], out = log_softmax(dinv*agg(h2')+b2)
    gemm_mfma_kernel<128, 4, 6, _Float16, true, false><<<gemm_blocks, 256, 0, stream>>>(
        bufB, bord2, dinv, bufC, N);
    agg2_kernel<<<(N + 3) / 4, 256, 0, stream>>>((const __half*)bufC, row_ptr, edges, dinv, b2,
                                                 out, N);
}

// Round 3
// 396.296 us; speedup vs baseline: 1.2456x; 1.2456x over previous
//
#include <hip/hip_runtime.h>
#include <hip/hip_fp16.h>

// GCN 2-layer forward. R1: multi-block scan. R2: fp16 intermediates.
// R3: wide-gather aggregation. R4: packed hist atomic + fp16 MFMA GEMMs.
// R5: reformulated normalization, packed 8B edges, self-loops in scan.
// R6: bucket-sort CSR build. R7: LDS-free fragment-ordered GEMM.
// R8: GEMM latency fix — full K-strip register prefetch + 16 rows/wave.
// R9: scatter latency fix — 2048 edges/block, int4 loads, ranks in registers.
// R10 (REVERTED): feature-chunked agg — L2-residency worked (FETCH 194->125MB)
//      but 8x per-edge metadata/VALU overhead + 32B gather granules tripled
//      dur. Lesson: touch each edge once, keep 256B coalesced row gathers.
// R11: agg MLP fix — agg1 at 43% HBM / 48% VALU / 73% occ was latency-bound
//      with only 2 gathers in flight per lane. Now 4 edges in flight per lane
//      in both agg kernels (step 16 / 32). Tail slots clamp to last edge ->
//      same-line L2 hits, no extra HBM traffic.

#define BLK 256
#define NPB 128          // nodes per bucket (dstlocal = dst & 127)
#define MAXBUCK 1024
#define FCAP 3072        // bucket_final LDS edge capacity
#define SCHUNK 2048      // edges per scatter block (8 per thread)

typedef _Float16 half8 __attribute__((ext_vector_type(8)));
typedef float f32x4 __attribute__((ext_vector_type(4)));

// --- 1. bucket histogram (fire-and-forget atomics, LDS-privatized) ---
__global__ __launch_bounds__(256) void bucket_hist_kernel(const int* __restrict__ dst, int E,
                                                          int nbuck, int* __restrict__ bhist) {
    __shared__ int lh[MAXBUCK];
    for (int i = threadIdx.x; i < nbuck; i += 256) lh[i] = 0;
    __syncthreads();
    if ((E & 3) == 0) {
        int E4 = E >> 2;
        for (int i = blockIdx.x * 256 + threadIdx.x; i < E4; i += gridDim.x * 256) {
            int4 dv = *(const int4*)(dst + i * 4);
            atomicAdd(&lh[dv.x >> 7], 1);
            atomicAdd(&lh[dv.y >> 7], 1);
            atomicAdd(&lh[dv.z >> 7], 1);
            atomicAdd(&lh[dv.w >> 7], 1);
        }
    } else {
        for (int e = blockIdx.x * 256 + threadIdx.x; e < E; e += gridDim.x * 256)
            atomicAdd(&lh[dst[e] >> 7], 1);
    }
    __syncthreads();
    for (int i = threadIdx.x; i < nbuck; i += 256)
        if (lh[i]) atomicAdd(&bhist[i], lh[i]);
}

// --- 2. dual exclusive scan over buckets ---
__global__ __launch_bounds__(256) void bucket_scan_kernel(const int* __restrict__ bhist,
                                                          int nbuck, int N,
                                                          int* __restrict__ ebBase,
                                                          int* __restrict__ bcursor,
                                                          int* __restrict__ outBase,
                                                          int* __restrict__ row_ptr) {
    __shared__ int sA[256], sB[256];
    int tid = threadIdx.x;
    int v1[4], v2[4];
    int s1 = 0, s2 = 0;
    #pragma unroll
    for (int j = 0; j < 4; j++) {
        int idx = tid * 4 + j;
        int h = (idx < nbuck) ? bhist[idx] : 0;
        int nodes = 0;
        if (idx < nbuck) {
            nodes = N - idx * NPB;
            nodes = nodes > NPB ? NPB : nodes;
            if (nodes < 0) nodes = 0;
        }
        v1[j] = h; v2[j] = h + nodes;
        s1 += v1[j]; s2 += v2[j];
    }
    sA[tid] = s1; sB[tid] = s2;
    __syncthreads();
    for (int off = 1; off < 256; off <<= 1) {
        int a = (tid >= off) ? sA[tid - off] : 0;
        int b = (tid >= off) ? sB[tid - off] : 0;
        __syncthreads();
        sA[tid] += a; sB[tid] += b;
        __syncthreads();
    }
    int run1 = sA[tid] - s1, run2 = sB[tid] - s2;
    #pragma unroll
    for (int j = 0; j < 4; j++) {
        int idx = tid * 4 + j;
        if (idx < nbuck) {
            ebBase[idx] = run1; bcursor[idx] = run1; outBase[idx] = run2;
        }
        run1 += v1[j]; run2 += v2[j];
    }
    if (tid == 255) { ebBase[nbuck] = run1; row_ptr[N] = run2; }
}

// --- 3. scatter edges into bucket-grouped edgesB ---
__global__ __launch_bounds__(256) void bucket_scatter_kernel(const int* __restrict__ src,
                                                             const int* __restrict__ dst,
                                                             const float* __restrict__ ew,
                                                             int* __restrict__ bcursor,
                                                             uint2* __restrict__ edgesB,
                                                             int E, int nbuck) {
    __shared__ int lh[MAXBUCK];
    __shared__ int lbase[MAXBUCK];
    const int tid = threadIdx.x;
    for (int i = tid; i < nbuck; i += 256) lh[i] = 0;
    __syncthreads();
    const int beg = blockIdx.x * SCHUNK;
    const bool vec = ((E & 3) == 0);
    int d[2][4], rk[2][4];
    #pragma unroll
    for (int j = 0; j < 2; j++) {
        int e = beg + j * 1024 + tid * 4;
        if (vec && e + 3 < E) {
            int4 dv = *(const int4*)(dst + e);
            d[j][0] = dv.x; d[j][1] = dv.y; d[j][2] = dv.z; d[j][3] = dv.w;
            #pragma unroll
            for (int k = 0; k < 4; k++) rk[j][k] = atomicAdd(&lh[d[j][k] >> 7], 1);
        } else {
            #pragma unroll
            for (int k = 0; k < 4; k++) {
                if (e + k < E) {
                    d[j][k] = dst[e + k];
                    rk[j][k] = atomicAdd(&lh[d[j][k] >> 7], 1);
                } else {
                    d[j][k] = -1;
                }
            }
        }
    }
    __syncthreads();
    for (int i = tid; i < nbuck; i += 256) {
        int c = lh[i];
        lbase[i] = c ? atomicAdd(&bcursor[i], c) : 0;
    }
    __syncthreads();
    #pragma unroll
    for (int j = 0; j < 2; j++) {
        int e = beg + j * 1024 + tid * 4;
        if (vec && e + 3 < E) {
            int4 sv = *(const int4*)(src + e);
            float4 wv = *(const float4*)(ew + e);
            int sa[4] = {sv.x, sv.y, sv.z, sv.w};
            float wa[4] = {wv.x, wv.y, wv.z, wv.w};
            #pragma unroll
            for (int k = 0; k < 4; k++) {
                int b = d[j][k] >> 7;
                edgesB[lbase[b] + rk[j][k]] =
                    make_uint2((unsigned)sa[k] | ((unsigned)(d[j][k] & 127) << 17),
                               __float_as_uint(wa[k]));
            }
        } else {
            #pragma unroll
            for (int k = 0; k < 4; k++) {
                if (d[j][k] >= 0) {
                    int b = d[j][k] >> 7;
                    edgesB[lbase[b] + rk[j][k]] =
                        make_uint2((unsigned)src[e + k] | ((unsigned)(d[j][k] & 127) << 17),
                                   __float_as_uint(ew[e + k]));
                }
            }
        }
    }
}

// --- 4. per-bucket finalize ---
__global__ __launch_bounds__(256) void bucket_final_kernel(const uint2* __restrict__ edgesB,
                                                           const int* __restrict__ ebBase,
                                                           const int* __restrict__ outBase,
                                                           int* __restrict__ row_ptr,
                                                           float* __restrict__ dinv,
                                                           uint2* __restrict__ edges,
                                                           int N, int nbuck) {
    __shared__ uint2 eb[FCAP];
    __shared__ int cnts[NPB];
    __shared__ float wsum[NPB];
    __shared__ int starts[NPB];
    int b = blockIdx.x;
    int tid = threadIdx.x;
    int beg = ebBase[b];
    int cnt = ebBase[b + 1] - beg;
    if (cnt > FCAP) cnt = FCAP;
    int node0 = b * NPB;
    int nn = N - node0; if (nn > NPB) nn = NPB;
    for (int i = tid; i < nn; i += 256) { cnts[i] = 0; wsum[i] = 0.f; }
    for (int i = tid; i < cnt; i += 256) eb[i] = edgesB[beg + i];
    __syncthreads();
    for (int i = tid; i < cnt; i += 256) {
        int dl = eb[i].x >> 17;
        atomicAdd(&cnts[dl], 1);
        atomicAdd(&wsum[dl], __uint_as_float(eb[i].y));
    }
    __syncthreads();
    if (tid < 64) {
        int i0 = 2 * tid, i1 = 2 * tid + 1;
        int c0 = (i0 < nn) ? cnts[i0] + 1 : 0;
        int c1 = (i1 < nn) ? cnts[i1] + 1 : 0;
        int s = c0 + c1;
        int incl = s;
        #pragma unroll
        for (int off = 1; off < 64; off <<= 1) {
            int t = __shfl_up(incl, off);
            if (tid >= off) incl += t;
        }
        int excl = incl - s;
        int outB = outBase[b];
        if (i0 < nn) starts[i0] = outB + excl;
        if (i1 < nn) starts[i1] = outB + excl + c0;
    }
    __syncthreads();
    for (int i = tid; i < nn; i += 256) {
        int rp = starts[i];
        int node = node0 + i;
        row_ptr[node] = rp;
        dinv[node] = rsqrtf(wsum[i] + 1.0f);
        edges[rp] = make_uint2((unsigned)node, __float_as_uint(1.0f));
        cnts[i] = 1;
    }
    __syncthreads();
    for (int i = tid; i < cnt; i += 256) {
        int dl = eb[i].x >> 17;
        int r = atomicAdd(&cnts[dl], 1);
        edges[starts[dl] + r] = make_uint2(eb[i].x & 0x1FFFFu, eb[i].y);
    }
}

// W[K][NN] fp32 -> Bord fragment order: Bord[((t*KS+ks)*64+lane)*8+j]
//   = W[ks*32+(lane>>4)*8+j][t*16+(lane&15)]
template<int K, int NT>
__global__ void convert_bord_kernel(const float* __restrict__ W, _Float16* __restrict__ Bord) {
    constexpr int NN = NT * 16;
    constexpr int KS = K / 32;
    int i = blockIdx.x * blockDim.x + threadIdx.x;
    if (i < NT * KS * 64 * 8) {
        int j = i & 7;
        int lane = (i >> 3) & 63;
        int ks = (i >> 9) % KS;
        int t = i / (KS * 512);
        int kk = ks * 32 + (lane >> 4) * 8 + j;
        int nnj = t * 16 + (lane & 15);
        Bord[i] = (_Float16)W[(size_t)kk * NN + nnj];
    }
}

// LDS-free MFMA GEMM, full K-strip register prefetch. One wave owns 16 rows.
// C[M,NN] = scale[m]*(A[M,K] @ B), B pre-shuffled to fragment order.
template<int K, int NT, int MINW, typename AT>
__global__ __launch_bounds__(256, MINW) void gemm_mfma_kernel(const AT* __restrict__ A,
                                                              const _Float16* __restrict__ Bord,
                                                              const float* __restrict__ scale,
                                                              _Float16* __restrict__ C, int M) {
    constexpr int NN = NT * 16;
    constexpr int KS = K / 32;
    const int wave_id = (blockIdx.x * blockDim.x + threadIdx.x) >> 6;
    const int lane = threadIdx.x & 63;
    const int quad = lane >> 4;
    const int nl = lane & 15;
    const int row_base = wave_id * 16;
    if (row_base >= M) return;
    const int m = min(row_base + nl, M - 1);

    // ---- prefetch the whole K-strip: all loads issued before first use ----
    float4 raw[KS][2];   // fp32 source path
    half8 afr[KS];       // fp16 source path
    if constexpr (sizeof(AT) == 4) {
        const float* ap = (const float*)A + (size_t)m * K + quad * 8;
        #pragma unroll
        for (int ks = 0; ks < KS; ks++) {
            raw[ks][0] = *(const float4*)(ap + ks * 32);
            raw[ks][1] = *(const float4*)(ap + ks * 32 + 4);
        }
    } else {
        const _Float16* ap = (const _Float16*)A + (size_t)m * K + quad * 8;
        #pragma unroll
        for (int ks = 0; ks < KS; ks++)
            afr[ks] = *(const half8*)(ap + ks * 32);
    }

    f32x4 acc[NT] = {};
    #pragma unroll
    for (int ks = 0; ks < KS; ks++) {
        half8 af;
        if constexpr (sizeof(AT) == 4) {
            af[0] = (_Float16)raw[ks][0].x; af[1] = (_Float16)raw[ks][0].y;
            af[2] = (_Float16)raw[ks][0].z; af[3] = (_Float16)raw[ks][0].w;
            af[4] = (_Float16)raw[ks][1].x; af[5] = (_Float16)raw[ks][1].y;
            af[6] = (_Float16)raw[ks][1].z; af[7] = (_Float16)raw[ks][1].w;
        } else {
            af = afr[ks];
        }
        #pragma unroll
        for (int t = 0; t < NT; t++) {
            half8 bf = *(const half8*)(Bord + ((size_t)(t * KS + ks) * 64 + lane) * 8);
            acc[t] = __builtin_amdgcn_mfma_f32_16x16x32_f16(af, bf, acc[t], 0, 0, 0);
        }
    }

    #pragma unroll
    for (int r = 0; r < 4; r++) {
        int grow = row_base + quad * 4 + r;
        if (grow < M) {
            float sc = scale[grow];
            #pragma unroll
            for (int t = 0; t < NT; t++)
                C[(size_t)grow * NN + t * 16 + nl] = (_Float16)(sc * acc[t][r]);
        }
    }
}

__device__ inline void accum8(float* acc, uint4 p, float v) {
    const __half2* q = (const __half2*)&p;
    #pragma unroll
    for (int k = 0; k < 4; k++) {
        float2 f = __half22float2(q[k]);
        acc[2 * k]     += v * f.x;
        acc[2 * k + 1] += v * f.y;
    }
}

// Layer-1 aggregation: out = relu(dinv[i]*sum(ew*h'[src]) + b1), fp16.
// R11: 4 edges in flight per lane (was 2) — metadata loads then gathers,
// all issued before any use. Clamped tail slots hit the last edge's line.
__global__ void agg1_kernel(const __half* __restrict__ h, const int* __restrict__ row_ptr,
                            const uint2* __restrict__ edges, const float* __restrict__ dinv,
                            const float* __restrict__ b1, __half* __restrict__ out, int n) {
    int node = blockIdx.x * (blockDim.x >> 6) + (threadIdx.x >> 6);
    int lane = threadIdx.x & 63;
    if (node >= n) return;
    int g = lane >> 4;
    int l = lane & 15;
    int beg = row_ptr[node], end = row_ptr[node + 1];
    float acc[8] = {};
    const __half* hb = h + l * 8;
    for (int e0 = beg; e0 < end; e0 += 16) {
        int eA = e0 + g, eB = e0 + 4 + g, eC = e0 + 8 + g, eD = e0 + 12 + g;
        int cA = min(eA, end - 1), cB = min(eB, end - 1);
        int cC = min(eC, end - 1), cD = min(eD, end - 1);
        uint2 mA = edges[cA], mB = edges[cB], mC = edges[cC], mD = edges[cD];
        float vA = (eA < end) ? __uint_as_float(mA.y) : 0.f;
        float vB = (eB < end) ? __uint_as_float(mB.y) : 0.f;
        float vC = (eC < end) ? __uint_as_float(mC.y) : 0.f;
        float vD = (eD < end) ? __uint_as_float(mD.y) : 0.f;
        uint4 pA = *(const uint4*)(hb + (size_t)mA.x * 128);
        uint4 pB = *(const uint4*)(hb + (size_t)mB.x * 128);
        uint4 pC = *(const uint4*)(hb + (size_t)mC.x * 128);
        uint4 pD = *(const uint4*)(hb + (size_t)mD.x * 128);
        accum8(acc, pA, vA);
        accum8(acc, pB, vB);
        accum8(acc, pC, vC);
        accum8(acc, pD, vD);
    }
    #pragma unroll
    for (int j = 0; j < 8; j++) {
        acc[j] += __shfl_xor(acc[j], 32);
        acc[j] += __shfl_xor(acc[j], 16);
    }
    if (g == 0) {
        float di = dinv[node];
        float4 b0 = *(const float4*)(b1 + l * 8);
        float4 b1v = *(const float4*)(b1 + l * 8 + 4);
        float r[8] = {di * acc[0] + b0.x, di * acc[1] + b0.y, di * acc[2] + b0.z,
                      di * acc[3] + b0.w, di * acc[4] + b1v.x, di * acc[5] + b1v.y,
                      di * acc[6] + b1v.z, di * acc[7] + b1v.w};
        #pragma unroll
        for (int j = 0; j < 8; j++) r[j] = r[j] > 0.f ? r[j] : 0.f;
        __half2 o[4];
        #pragma unroll
        for (int k = 0; k < 4; k++) o[k] = __floats2half2_rn(r[2 * k], r[2 * k + 1]);
        *(uint4*)(out + (size_t)node * 128 + l * 8) = *(uint4*)o;
    }
}

// Layer-2 aggregation + log_softmax. R11: 4 edges in flight per lane.
__global__ void agg2_kernel(const __half* __restrict__ h2, const int* __restrict__ row_ptr,
                            const uint2* __restrict__ edges, const float* __restrict__ dinv,
                            const float* __restrict__ b2, float* __restrict__ out, int n) {
    int node = blockIdx.x * (blockDim.x >> 6) + (threadIdx.x >> 6);
    int lane = threadIdx.x & 63;
    if (node >= n) return;
    int g = lane >> 3;
    int l = lane & 7;
    int beg = row_ptr[node], end = row_ptr[node + 1];
    float acc[8] = {};
    const __half* hb = h2 + l * 8;
    for (int e0 = beg; e0 < end; e0 += 32) {
        int eA = e0 + g, eB = e0 + 8 + g, eC = e0 + 16 + g, eD = e0 + 24 + g;
        int cA = min(eA, end - 1), cB = min(eB, end - 1);
        int cC = min(eC, end - 1), cD = min(eD, end - 1);
        uint2 mA = edges[cA], mB = edges[cB], mC = edges[cC], mD = edges[cD];
        float vA = (eA < end) ? __uint_as_float(mA.y) : 0.f;
        float vB = (eB < end) ? __uint_as_float(mB.y) : 0.f;
        float vC = (eC < end) ? __uint_as_float(mC.y) : 0.f;
        float vD = (eD < end) ? __uint_as_float(mD.y) : 0.f;
        uint4 pA = *(const uint4*)(hb + (size_t)mA.x * 64);
        uint4 pB = *(const uint4*)(hb + (size_t)mB.x * 64);
        uint4 pC = *(const uint4*)(hb + (size_t)mC.x * 64);
        uint4 pD = *(const uint4*)(hb + (size_t)mD.x * 64);
        accum8(acc, pA, vA);
        accum8(acc, pB, vB);
        accum8(acc, pC, vC);
        accum8(acc, pD, vD);
    }
    #pragma unroll
    for (int j = 0; j < 8; j++) {
        acc[j] += __shfl_xor(acc[j], 32);
        acc[j] += __shfl_xor(acc[j], 16);
        acc[j] += __shfl_xor(acc[j], 8);
    }
    float di = dinv[node];
    float4 b0 = *(const float4*)(b2 + l * 8);
    float4 b1v = *(const float4*)(b2 + l * 8 + 4);
    acc[0] = di * acc[0] + b0.x;  acc[1] = di * acc[1] + b0.y;
    acc[2] = di * acc[2] + b0.z;  acc[3] = di * acc[3] + b0.w;
    acc[4] = di * acc[4] + b1v.x; acc[5] = di * acc[5] + b1v.y;
    acc[6] = di * acc[6] + b1v.z; acc[7] = di * acc[7] + b1v.w;
    float m = acc[0];
    #pragma unroll
    for (int j = 1; j < 8; j++) m = fmaxf(m, acc[j]);
    #pragma unroll
    for (int off = 1; off < 8; off <<= 1) m = fmaxf(m, __shfl_xor(m, off));
    float s = 0.f;
    #pragma unroll
    for (int j = 0; j < 8; j++) s += expf(acc[j] - m);
    #pragma unroll
    for (int off = 1; off < 8; off <<= 1) s += __shfl_xor(s, off);
    float ls = m + logf(s);
    if (g == 0) {
        float* op = out + (size_t)node * 64 + l * 8;
        *(float4*)(op)     = make_float4(acc[0] - ls, acc[1] - ls, acc[2] - ls, acc[3] - ls);
        *(float4*)(op + 4) = make_float4(acc[4] - ls, acc[5] - ls, acc[6] - ls, acc[7] - ls);
    }
}

extern "C" void kernel_launch(void* const* d_in, const int* in_sizes, int n_in,
                              void* d_out, int out_size, void* d_ws, size_t ws_size,
                              hipStream_t stream) {
    const float* x  = (const float*)d_in[0];
    const int*   ei = (const int*)d_in[1];
    const float* ew = (const float*)d_in[2];
    const float* W1 = (const float*)d_in[3];
    const float* b1 = (const float*)d_in[4];
    const float* W2 = (const float*)d_in[5];
    const float* b2 = (const float*)d_in[6];
    float* out = (float*)d_out;

    const int N = in_sizes[0] / 256;
    const int E = in_sizes[1] / 2;
    const int Et = E + N;
    const int* src = ei;
    const int* dst = ei + E;
    const int nbuck = (N + NPB - 1) / NPB;

    char* w = (char*)d_ws;
    size_t off = 0;
    auto carve = [&](size_t bytes) {
        void* p = w + off;
        off = (off + bytes + 255) & ~(size_t)255;
        return p;
    };
    int*      bhist   = (int*)  carve((size_t)MAXBUCK * 4);
    int*      ebBase  = (int*)  carve((size_t)(MAXBUCK + 1) * 4);
    int*      bcursor = (int*)  carve((size_t)MAXBUCK * 4);
    int*      outBase = (int*)  carve((size_t)MAXBUCK * 4);
    int*      row_ptr = (int*)  carve((size_t)(N + 1) * 4);
    float*    dinv    = (float*)carve((size_t)N * 4);
    uint2*    edgesB  = (uint2*)carve((size_t)E * 8);
    uint2*    edges   = (uint2*)carve((size_t)Et * 8);
    _Float16* bord1   = (_Float16*)carve((size_t)256 * 128 * 2);
    _Float16* bord2   = (_Float16*)carve((size_t)128 * 64 * 2);
    _Float16* bufA    = (_Float16*)carve((size_t)N * 128 * 2);  // h'; later h2' (aliased)
    _Float16* bufB    = (_Float16*)carve((size_t)N * 128 * 2);  // h1
    _Float16* bufC    = bufA;

    // 1. bucket-sort CSR build
    hipMemsetAsync(bhist, 0, (size_t)nbuck * 4, stream);
    bucket_hist_kernel<<<256, 256, 0, stream>>>(dst, E, nbuck, bhist);
    bucket_scan_kernel<<<1, 256, 0, stream>>>(bhist, nbuck, N, ebBase, bcursor, outBase, row_ptr);
    const int scat_blocks = (E + SCHUNK - 1) / SCHUNK;
    bucket_scatter_kernel<<<scat_blocks, 256, 0, stream>>>(src, dst, ew, bcursor, edgesB, E, nbuck);
    bucket_final_kernel<<<nbuck, 256, 0, stream>>>(edgesB, ebBase, outBase, row_ptr, dinv,
                                                   edges, N, nbuck);

    // weight reorders (tiny)
    convert_bord_kernel<256, 8><<<(256 * 128 + 255) / 256, 256, 0, stream>>>(W1, bord1);
    convert_bord_kernel<128, 4><<<(128 * 64 + 255) / 256, 256, 0, stream>>>(W2, bord2);

    // 2. Layer 1: h' = dinv * (x @ W1), h1 = relu(dinv*agg(h')+b1)
    const int waves = (N + 15) / 16;            // 16 rows per wave
    const int gemm_blocks = (waves + 3) / 4;    // 4 waves per block
    gemm_mfma_kernel<256, 8, 4, float><<<gemm_blocks, 256, 0, stream>>>(x, bord1, dinv, bufA, N);
    agg1_kernel<<<(N + 3) / 4, 256, 0, stream>>>((const __half*)bufA, row_ptr, edges, dinv, b1,
                                                 (__half*)bufB, N);

    // 3. Layer 2: h2' = dinv * (h1 @ W2), out = log_softmax(dinv*agg(h2')+b2)
    gemm_mfma_kernel<128, 4, 6, _Float16><<<gemm_blocks, 256, 0, stream>>>(bufB, bord2, dinv,
                                                                           bufC, N);
    agg2_kernel<<<(N + 3) / 4, 256, 0, stream>>>((const __half*)bufC, row_ptr, edges, dinv, b2,
                                                 out, N);
}

// Round 4
// 379.351 us; speedup vs baseline: 1.3013x; 1.0447x over previous
//
#include <hip/hip_runtime.h>
#include <hip/hip_fp16.h>

// GCN 2-layer forward. R1: multi-block scan. R2: fp16 intermediates.
// R3: wide-gather aggregation. R4: packed hist atomic + fp16 MFMA GEMMs.
// R5: reformulated normalization, packed 8B edges, self-loops in scan.
// R6: bucket-sort CSR build. R7: LDS-free fragment-ordered GEMM.
// R8: GEMM latency fix — full K-strip register prefetch + 16 rows/wave.
// R9: scatter latency fix — 2048 edges/block, int4 loads, ranks in registers.
// R10 (REVERTED): feature-chunked agg — L2 residency worked but 8x per-edge
//      overhead tripled dur. Lesson: touch each edge once, 256B row gathers.
// R11: 4 edges in flight per lane. Only -3%: waste was structural.
// R12: agg restructure — one node per 16-lane quarter (agg1) / 8-lane octet
//      (agg2), full feature row per group, edges sequential 4-deep.
//      Slots/node 32 -> ~20 (47% clamp-dupe gathers eliminated), no
//      accumulation shuffle, 16 rows in flight per wave (was 4).
//      Divergent quarters are exec-masked -> no wasted memory traffic.
//      convert_bord kernels fused into one launch.

#define BLK 256
#define NPB 128          // nodes per bucket (dstlocal = dst & 127)
#define MAXBUCK 1024
#define FCAP 3072        // bucket_final LDS edge capacity
#define SCHUNK 2048      // edges per scatter block (8 per thread)

typedef _Float16 half8 __attribute__((ext_vector_type(8)));
typedef float f32x4 __attribute__((ext_vector_type(4)));

// --- 1. bucket histogram (fire-and-forget atomics, LDS-privatized) ---
__global__ __launch_bounds__(256) void bucket_hist_kernel(const int* __restrict__ dst, int E,
                                                          int nbuck, int* __restrict__ bhist) {
    __shared__ int lh[MAXBUCK];
    for (int i = threadIdx.x; i < nbuck; i += 256) lh[i] = 0;
    __syncthreads();
    if ((E & 3) == 0) {
        int E4 = E >> 2;
        for (int i = blockIdx.x * 256 + threadIdx.x; i < E4; i += gridDim.x * 256) {
            int4 dv = *(const int4*)(dst + i * 4);
            atomicAdd(&lh[dv.x >> 7], 1);
            atomicAdd(&lh[dv.y >> 7], 1);
            atomicAdd(&lh[dv.z >> 7], 1);
            atomicAdd(&lh[dv.w >> 7], 1);
        }
    } else {
        for (int e = blockIdx.x * 256 + threadIdx.x; e < E; e += gridDim.x * 256)
            atomicAdd(&lh[dst[e] >> 7], 1);
    }
    __syncthreads();
    for (int i = threadIdx.x; i < nbuck; i += 256)
        if (lh[i]) atomicAdd(&bhist[i], lh[i]);
}

// --- 2. dual exclusive scan over buckets ---
__global__ __launch_bounds__(256) void bucket_scan_kernel(const int* __restrict__ bhist,
                                                          int nbuck, int N,
                                                          int* __restrict__ ebBase,
                                                          int* __restrict__ bcursor,
                                                          int* __restrict__ outBase,
                                                          int* __restrict__ row_ptr) {
    __shared__ int sA[256], sB[256];
    int tid = threadIdx.x;
    int v1[4], v2[4];
    int s1 = 0, s2 = 0;
    #pragma unroll
    for (int j = 0; j < 4; j++) {
        int idx = tid * 4 + j;
        int h = (idx < nbuck) ? bhist[idx] : 0;
        int nodes = 0;
        if (idx < nbuck) {
            nodes = N - idx * NPB;
            nodes = nodes > NPB ? NPB : nodes;
            if (nodes < 0) nodes = 0;
        }
        v1[j] = h; v2[j] = h + nodes;
        s1 += v1[j]; s2 += v2[j];
    }
    sA[tid] = s1; sB[tid] = s2;
    __syncthreads();
    for (int off = 1; off < 256; off <<= 1) {
        int a = (tid >= off) ? sA[tid - off] : 0;
        int b = (tid >= off) ? sB[tid - off] : 0;
        __syncthreads();
        sA[tid] += a; sB[tid] += b;
        __syncthreads();
    }
    int run1 = sA[tid] - s1, run2 = sB[tid] - s2;
    #pragma unroll
    for (int j = 0; j < 4; j++) {
        int idx = tid * 4 + j;
        if (idx < nbuck) {
            ebBase[idx] = run1; bcursor[idx] = run1; outBase[idx] = run2;
        }
        run1 += v1[j]; run2 += v2[j];
    }
    if (tid == 255) { ebBase[nbuck] = run1; row_ptr[N] = run2; }
}

// --- 3. scatter edges into bucket-grouped edgesB ---
__global__ __launch_bounds__(256) void bucket_scatter_kernel(const int* __restrict__ src,
                                                             const int* __restrict__ dst,
                                                             const float* __restrict__ ew,
                                                             int* __restrict__ bcursor,
                                                             uint2* __restrict__ edgesB,
                                                             int E, int nbuck) {
    __shared__ int lh[MAXBUCK];
    __shared__ int lbase[MAXBUCK];
    const int tid = threadIdx.x;
    for (int i = tid; i < nbuck; i += 256) lh[i] = 0;
    __syncthreads();
    const int beg = blockIdx.x * SCHUNK;
    const bool vec = ((E & 3) == 0);
    int d[2][4], rk[2][4];
    #pragma unroll
    for (int j = 0; j < 2; j++) {
        int e = beg + j * 1024 + tid * 4;
        if (vec && e + 3 < E) {
            int4 dv = *(const int4*)(dst + e);
            d[j][0] = dv.x; d[j][1] = dv.y; d[j][2] = dv.z; d[j][3] = dv.w;
            #pragma unroll
            for (int k = 0; k < 4; k++) rk[j][k] = atomicAdd(&lh[d[j][k] >> 7], 1);
        } else {
            #pragma unroll
            for (int k = 0; k < 4; k++) {
                if (e + k < E) {
                    d[j][k] = dst[e + k];
                    rk[j][k] = atomicAdd(&lh[d[j][k] >> 7], 1);
                } else {
                    d[j][k] = -1;
                }
            }
        }
    }
    __syncthreads();
    for (int i = tid; i < nbuck; i += 256) {
        int c = lh[i];
        lbase[i] = c ? atomicAdd(&bcursor[i], c) : 0;
    }
    __syncthreads();
    #pragma unroll
    for (int j = 0; j < 2; j++) {
        int e = beg + j * 1024 + tid * 4;
        if (vec && e + 3 < E) {
            int4 sv = *(const int4*)(src + e);
            float4 wv = *(const float4*)(ew + e);
            int sa[4] = {sv.x, sv.y, sv.z, sv.w};
            float wa[4] = {wv.x, wv.y, wv.z, wv.w};
            #pragma unroll
            for (int k = 0; k < 4; k++) {
                int b = d[j][k] >> 7;
                edgesB[lbase[b] + rk[j][k]] =
                    make_uint2((unsigned)sa[k] | ((unsigned)(d[j][k] & 127) << 17),
                               __float_as_uint(wa[k]));
            }
        } else {
            #pragma unroll
            for (int k = 0; k < 4; k++) {
                if (d[j][k] >= 0) {
                    int b = d[j][k] >> 7;
                    edgesB[lbase[b] + rk[j][k]] =
                        make_uint2((unsigned)src[e + k] | ((unsigned)(d[j][k] & 127) << 17),
                                   __float_as_uint(ew[e + k]));
                }
            }
        }
    }
}

// --- 4. per-bucket finalize ---
__global__ __launch_bounds__(256) void bucket_final_kernel(const uint2* __restrict__ edgesB,
                                                           const int* __restrict__ ebBase,
                                                           const int* __restrict__ outBase,
                                                           int* __restrict__ row_ptr,
                                                           float* __restrict__ dinv,
                                                           uint2* __restrict__ edges,
                                                           int N, int nbuck) {
    __shared__ uint2 eb[FCAP];
    __shared__ int cnts[NPB];
    __shared__ float wsum[NPB];
    __shared__ int starts[NPB];
    int b = blockIdx.x;
    int tid = threadIdx.x;
    int beg = ebBase[b];
    int cnt = ebBase[b + 1] - beg;
    if (cnt > FCAP) cnt = FCAP;
    int node0 = b * NPB;
    int nn = N - node0; if (nn > NPB) nn = NPB;
    for (int i = tid; i < nn; i += 256) { cnts[i] = 0; wsum[i] = 0.f; }
    for (int i = tid; i < cnt; i += 256) eb[i] = edgesB[beg + i];
    __syncthreads();
    for (int i = tid; i < cnt; i += 256) {
        int dl = eb[i].x >> 17;
        atomicAdd(&cnts[dl], 1);
        atomicAdd(&wsum[dl], __uint_as_float(eb[i].y));
    }
    __syncthreads();
    if (tid < 64) {
        int i0 = 2 * tid, i1 = 2 * tid + 1;
        int c0 = (i0 < nn) ? cnts[i0] + 1 : 0;
        int c1 = (i1 < nn) ? cnts[i1] + 1 : 0;
        int s = c0 + c1;
        int incl = s;
        #pragma unroll
        for (int off = 1; off < 64; off <<= 1) {
            int t = __shfl_up(incl, off);
            if (tid >= off) incl += t;
        }
        int excl = incl - s;
        int outB = outBase[b];
        if (i0 < nn) starts[i0] = outB + excl;
        if (i1 < nn) starts[i1] = outB + excl + c0;
    }
    __syncthreads();
    for (int i = tid; i < nn; i += 256) {
        int rp = starts[i];
        int node = node0 + i;
        row_ptr[node] = rp;
        dinv[node] = rsqrtf(wsum[i] + 1.0f);
        edges[rp] = make_uint2((unsigned)node, __float_as_uint(1.0f));
        cnts[i] = 1;
    }
    __syncthreads();
    for (int i = tid; i < cnt; i += 256) {
        int dl = eb[i].x >> 17;
        int r = atomicAdd(&cnts[dl], 1);
        edges[starts[dl] + r] = make_uint2(eb[i].x & 0x1FFFFu, eb[i].y);
    }
}

// W[K][NN] fp32 -> Bord fragment order: Bord[((t*KS+ks)*64+lane)*8+j]
//   = W[ks*32+(lane>>4)*8+j][t*16+(lane&15)]
template<int K, int NT>
__device__ inline void bord_fill(const float* __restrict__ W, _Float16* __restrict__ Bord,
                                 int i) {
    constexpr int NN = NT * 16;
    constexpr int KS = K / 32;
    int j = i & 7;
    int lane = (i >> 3) & 63;
    int ks = (i >> 9) % KS;
    int t = i / (KS * 512);
    int kk = ks * 32 + (lane >> 4) * 8 + j;
    int nnj = t * 16 + (lane & 15);
    Bord[i] = (_Float16)W[(size_t)kk * NN + nnj];
}

// fused: both weight reorders in one launch (sizes 32768 + 8192)
__global__ void convert_bord_both_kernel(const float* __restrict__ W1, _Float16* __restrict__ B1,
                                         const float* __restrict__ W2, _Float16* __restrict__ B2) {
    int i = blockIdx.x * blockDim.x + threadIdx.x;
    if (i < 32768) bord_fill<256, 8>(W1, B1, i);
    else if (i < 32768 + 8192) bord_fill<128, 4>(W2, B2, i - 32768);
}

// LDS-free MFMA GEMM, full K-strip register prefetch. One wave owns 16 rows.
// C[M,NN] = scale[m]*(A[M,K] @ B), B pre-shuffled to fragment order.
template<int K, int NT, int MINW, typename AT>
__global__ __launch_bounds__(256, MINW) void gemm_mfma_kernel(const AT* __restrict__ A,
                                                              const _Float16* __restrict__ Bord,
                                                              const float* __restrict__ scale,
                                                              _Float16* __restrict__ C, int M) {
    constexpr int NN = NT * 16;
    constexpr int KS = K / 32;
    const int wave_id = (blockIdx.x * blockDim.x + threadIdx.x) >> 6;
    const int lane = threadIdx.x & 63;
    const int quad = lane >> 4;
    const int nl = lane & 15;
    const int row_base = wave_id * 16;
    if (row_base >= M) return;
    const int m = min(row_base + nl, M - 1);

    // ---- prefetch the whole K-strip: all loads issued before first use ----
    float4 raw[KS][2];   // fp32 source path
    half8 afr[KS];       // fp16 source path
    if constexpr (sizeof(AT) == 4) {
        const float* ap = (const float*)A + (size_t)m * K + quad * 8;
        #pragma unroll
        for (int ks = 0; ks < KS; ks++) {
            raw[ks][0] = *(const float4*)(ap + ks * 32);
            raw[ks][1] = *(const float4*)(ap + ks * 32 + 4);
        }
    } else {
        const _Float16* ap = (const _Float16*)A + (size_t)m * K + quad * 8;
        #pragma unroll
        for (int ks = 0; ks < KS; ks++)
            afr[ks] = *(const half8*)(ap + ks * 32);
    }

    f32x4 acc[NT] = {};
    #pragma unroll
    for (int ks = 0; ks < KS; ks++) {
        half8 af;
        if constexpr (sizeof(AT) == 4) {
            af[0] = (_Float16)raw[ks][0].x; af[1] = (_Float16)raw[ks][0].y;
            af[2] = (_Float16)raw[ks][0].z; af[3] = (_Float16)raw[ks][0].w;
            af[4] = (_Float16)raw[ks][1].x; af[5] = (_Float16)raw[ks][1].y;
            af[6] = (_Float16)raw[ks][1].z; af[7] = (_Float16)raw[ks][1].w;
        } else {
            af = afr[ks];
        }
        #pragma unroll
        for (int t = 0; t < NT; t++) {
            half8 bf = *(const half8*)(Bord + ((size_t)(t * KS + ks) * 64 + lane) * 8);
            acc[t] = __builtin_amdgcn_mfma_f32_16x16x32_f16(af, bf, acc[t], 0, 0, 0);
        }
    }

    #pragma unroll
    for (int r = 0; r < 4; r++) {
        int grow = row_base + quad * 4 + r;
        if (grow < M) {
            float sc = scale[grow];
            #pragma unroll
            for (int t = 0; t < NT; t++)
                C[(size_t)grow * NN + t * 16 + nl] = (_Float16)(sc * acc[t][r]);
        }
    }
}

__device__ inline void accum8(float* acc, uint4 p, float v) {
    const __half2* q = (const __half2*)&p;
    #pragma unroll
    for (int k = 0; k < 4; k++) {
        float2 f = __half22float2(q[k]);
        acc[2 * k]     += v * f.x;
        acc[2 * k + 1] += v * f.y;
    }
}

// Layer-1 aggregation: out = relu(dinv[i]*sum(ew*h'[src]) + b1), fp16.
// R12: one node per 16-lane quarter (full 128-feature row per quarter),
// edges sequential 4-deep. No shuffle. Tail waste <=3 slots. Divergent
// quarters are exec-masked (no memory traffic).
__global__ __launch_bounds__(256) void agg1_kernel(const __half* __restrict__ h,
                                                   const int* __restrict__ row_ptr,
                                                   const uint2* __restrict__ edges,
                                                   const float* __restrict__ dinv,
                                                   const float* __restrict__ b1,
                                                   __half* __restrict__ out, int n) {
    const int wid = (blockIdx.x * blockDim.x + threadIdx.x) >> 6;
    const int lane = threadIdx.x & 63;
    const int q = lane >> 4;    // quarter = node slot
    const int l = lane & 15;    // feature lane (8 features each)
    const int node = wid * 4 + q;
    if (node >= n) return;
    const int beg = row_ptr[node], end = row_ptr[node + 1];
    float acc[8] = {};
    const __half* hb = h + l * 8;
    for (int e0 = beg; e0 < end; e0 += 4) {
        int e1 = min(e0 + 1, end - 1), e2 = min(e0 + 2, end - 1), e3 = min(e0 + 3, end - 1);
        uint2 mA = edges[e0], mB = edges[e1], mC = edges[e2], mD = edges[e3];
        float vA = __uint_as_float(mA.y);
        float vB = (e0 + 1 < end) ? __uint_as_float(mB.y) : 0.f;
        float vC = (e0 + 2 < end) ? __uint_as_float(mC.y) : 0.f;
        float vD = (e0 + 3 < end) ? __uint_as_float(mD.y) : 0.f;
        uint4 pA = *(const uint4*)(hb + (size_t)mA.x * 128);
        uint4 pB = *(const uint4*)(hb + (size_t)mB.x * 128);
        uint4 pC = *(const uint4*)(hb + (size_t)mC.x * 128);
        uint4 pD = *(const uint4*)(hb + (size_t)mD.x * 128);
        accum8(acc, pA, vA);
        accum8(acc, pB, vB);
        accum8(acc, pC, vC);
        accum8(acc, pD, vD);
    }
    const float di = dinv[node];
    const float4 b0 = *(const float4*)(b1 + l * 8);
    const float4 b1v = *(const float4*)(b1 + l * 8 + 4);
    float r[8] = {di * acc[0] + b0.x, di * acc[1] + b0.y, di * acc[2] + b0.z,
                  di * acc[3] + b0.w, di * acc[4] + b1v.x, di * acc[5] + b1v.y,
                  di * acc[6] + b1v.z, di * acc[7] + b1v.w};
    #pragma unroll
    for (int j = 0; j < 8; j++) r[j] = r[j] > 0.f ? r[j] : 0.f;
    __half2 o[4];
    #pragma unroll
    for (int k = 0; k < 4; k++) o[k] = __floats2half2_rn(r[2 * k], r[2 * k + 1]);
    *(uint4*)(out + (size_t)node * 128 + l * 8) = *(uint4*)o;
}

// Layer-2 aggregation + log_softmax.
// R12: one node per 8-lane octet (full 64-feature row), edges sequential
// 4-deep. Only the softmax reduce shuffles (3 stages within octet).
__global__ __launch_bounds__(256) void agg2_kernel(const __half* __restrict__ h2,
                                                   const int* __restrict__ row_ptr,
                                                   const uint2* __restrict__ edges,
                                                   const float* __restrict__ dinv,
                                                   const float* __restrict__ b2,
                                                   float* __restrict__ out, int n) {
    const int wid = (blockIdx.x * blockDim.x + threadIdx.x) >> 6;
    const int lane = threadIdx.x & 63;
    const int o8 = lane >> 3;   // octet = node slot
    const int l = lane & 7;     // feature lane (8 features each)
    const int node = wid * 8 + o8;
    if (node >= n) return;
    const int beg = row_ptr[node], end = row_ptr[node + 1];
    float acc[8] = {};
    const __half* hb = h2 + l * 8;
    for (int e0 = beg; e0 < end; e0 += 4) {
        int e1 = min(e0 + 1, end - 1), e2 = min(e0 + 2, end - 1), e3 = min(e0 + 3, end - 1);
        uint2 mA = edges[e0], mB = edges[e1], mC = edges[e2], mD = edges[e3];
        float vA = __uint_as_float(mA.y);
        float vB = (e0 + 1 < end) ? __uint_as_float(mB.y) : 0.f;
        float vC = (e0 + 2 < end) ? __uint_as_float(mC.y) : 0.f;
        float vD = (e0 + 3 < end) ? __uint_as_float(mD.y) : 0.f;
        uint4 pA = *(const uint4*)(hb + (size_t)mA.x * 64);
        uint4 pB = *(const uint4*)(hb + (size_t)mB.x * 64);
        uint4 pC = *(const uint4*)(hb + (size_t)mC.x * 64);
        uint4 pD = *(const uint4*)(hb + (size_t)mD.x * 64);
        accum8(acc, pA, vA);
        accum8(acc, pB, vB);
        accum8(acc, pC, vC);
        accum8(acc, pD, vD);
    }
    const float di = dinv[node];
    const float4 b0 = *(const float4*)(b2 + l * 8);
    const float4 b1v = *(const float4*)(b2 + l * 8 + 4);
    acc[0] = di * acc[0] + b0.x;  acc[1] = di * acc[1] + b0.y;
    acc[2] = di * acc[2] + b0.z;  acc[3] = di * acc[3] + b0.w;
    acc[4] = di * acc[4] + b1v.x; acc[5] = di * acc[5] + b1v.y;
    acc[6] = di * acc[6] + b1v.z; acc[7] = di * acc[7] + b1v.w;
    float m = acc[0];
    #pragma unroll
    for (int j = 1; j < 8; j++) m = fmaxf(m, acc[j]);
    #pragma unroll
    for (int off = 1; off < 8; off <<= 1) m = fmaxf(m, __shfl_xor(m, off));
    float s = 0.f;
    #pragma unroll
    for (int j = 0; j < 8; j++) s += expf(acc[j] - m);
    #pragma unroll
    for (int off = 1; off < 8; off <<= 1) s += __shfl_xor(s, off);
    float ls = m + logf(s);
    float* op = out + (size_t)node * 64 + l * 8;
    *(float4*)(op)     = make_float4(acc[0] - ls, acc[1] - ls, acc[2] - ls, acc[3] - ls);
    *(float4*)(op + 4) = make_float4(acc[4] - ls, acc[5] - ls, acc[6] - ls, acc[7] - ls);
}

extern "C" void kernel_launch(void* const* d_in, const int* in_sizes, int n_in,
                              void* d_out, int out_size, void* d_ws, size_t ws_size,
                              hipStream_t stream) {
    const float* x  = (const float*)d_in[0];
    const int*   ei = (const int*)d_in[1];
    const float* ew = (const float*)d_in[2];
    const float* W1 = (const float*)d_in[3];
    const float* b1 = (const float*)d_in[4];
    const float* W2 = (const float*)d_in[5];
    const float* b2 = (const float*)d_in[6];
    float* out = (float*)d_out;

    const int N = in_sizes[0] / 256;
    const int E = in_sizes[1] / 2;
    const int Et = E + N;
    const int* src = ei;
    const int* dst = ei + E;
    const int nbuck = (N + NPB - 1) / NPB;

    char* w = (char*)d_ws;
    size_t off = 0;
    auto carve = [&](size_t bytes) {
        void* p = w + off;
        off = (off + bytes + 255) & ~(size_t)255;
        return p;
    };
    int*      bhist   = (int*)  carve((size_t)MAXBUCK * 4);
    int*      ebBase  = (int*)  carve((size_t)(MAXBUCK + 1) * 4);
    int*      bcursor = (int*)  carve((size_t)MAXBUCK * 4);
    int*      outBase = (int*)  carve((size_t)MAXBUCK * 4);
    int*      row_ptr = (int*)  carve((size_t)(N + 1) * 4);
    float*    dinv    = (float*)carve((size_t)N * 4);
    uint2*    edgesB  = (uint2*)carve((size_t)E * 8);
    uint2*    edges   = (uint2*)carve((size_t)Et * 8);
    _Float16* bord1   = (_Float16*)carve((size_t)256 * 128 * 2);
    _Float16* bord2   = (_Float16*)carve((size_t)128 * 64 * 2);
    _Float16* bufA    = (_Float16*)carve((size_t)N * 128 * 2);  // h'; later h2' (aliased)
    _Float16* bufB    = (_Float16*)carve((size_t)N * 128 * 2);  // h1
    _Float16* bufC    = bufA;

    // 1. bucket-sort CSR build
    hipMemsetAsync(bhist, 0, (size_t)nbuck * 4, stream);
    bucket_hist_kernel<<<256, 256, 0, stream>>>(dst, E, nbuck, bhist);
    bucket_scan_kernel<<<1, 256, 0, stream>>>(bhist, nbuck, N, ebBase, bcursor, outBase, row_ptr);
    const int scat_blocks = (E + SCHUNK - 1) / SCHUNK;
    bucket_scatter_kernel<<<scat_blocks, 256, 0, stream>>>(src, dst, ew, bcursor, edgesB, E, nbuck);
    bucket_final_kernel<<<nbuck, 256, 0, stream>>>(edgesB, ebBase, outBase, row_ptr, dinv,
                                                   edges, N, nbuck);

    // weight reorders (tiny, fused)
    convert_bord_both_kernel<<<(32768 + 8192 + 255) / 256, 256, 0, stream>>>(W1, bord1, W2, bord2);

    // 2. Layer 1: h' = dinv * (x @ W1), h1 = relu(dinv*agg(h')+b1)
    const int waves = (N + 15) / 16;            // 16 rows per wave
    const int gemm_blocks = (waves + 3) / 4;    // 4 waves per block
    gemm_mfma_kernel<256, 8, 4, float><<<gemm_blocks, 256, 0, stream>>>(x, bord1, dinv, bufA, N);
    agg1_kernel<<<(N + 15) / 16, 256, 0, stream>>>((const __half*)bufA, row_ptr, edges, dinv, b1,
                                                   (__half*)bufB, N);

    // 3. Layer 2: h2' = dinv * (h1 @ W2), out = log_softmax(dinv*agg(h2')+b2)
    gemm_mfma_kernel<128, 4, 6, _Float16><<<gemm_blocks, 256, 0, stream>>>(bufB, bord2, dinv,
                                                                           bufC, N);
    agg2_kernel<<<(N + 31) / 32, 256, 0, stream>>>((const __half*)bufC, row_ptr, edges, dinv, b2,
                                                   out, N);
}

// Round 5
// 367.796 us; speedup vs baseline: 1.3422x; 1.0314x over previous
//
#include <hip/hip_runtime.h>
#include <hip/hip_fp16.h>

// GCN 2-layer forward. R1: multi-block scan. R2: fp16 intermediates.
// R3: wide-gather aggregation. R4: packed hist atomic + fp16 MFMA GEMMs.
// R5: reformulated normalization, packed 8B edges, self-loops in scan.
// R6: bucket-sort CSR build. R7: LDS-free fragment-ordered GEMM.
// R8: GEMM latency fix — full K-strip register prefetch + 16 rows/wave.
// R9: scatter latency fix — 2048 edges/block, int4 loads, ranks in registers.
// R10 (REVERTED): feature-chunked agg — 8x per-edge overhead tripled dur.
// R11/R12: agg restructure (node-per-quarter, 4-deep) — VALU waste removed
//      (VALUBusy 56->37%) but dur flat. VGPR_Count=32 proved the compiler
//      serialized the pipeline to ~1-2 gathers in flight (latency-bound).
// R13: (a) agg pipeline made real — 8 edges in flight, fully-unrolled
//      compile-time-indexed arrays, __launch_bounds__(256,4) for ~128-VGPR
//      budget (16 waves/CU x 8 gathers = ~130KB in flight per CU >> latency
//      requirement). (b) hist pass deleted — edgesB over-allocated at FCAP
//      slots/bucket, scatter bumps zeroed bcursor directly, scan runs after
//      scatter. Saves a 6.4MB dst read + 1.6M LDS atomics + one launch.

#define BLK 256
#define NPB 128          // nodes per bucket (dstlocal = dst & 127)
#define MAXBUCK 1024
#define FCAP 3072        // per-bucket edgesB capacity / final LDS capacity
#define SCHUNK 2048      // edges per scatter block (8 per thread)

typedef _Float16 half8 __attribute__((ext_vector_type(8)));
typedef float f32x4 __attribute__((ext_vector_type(4)));

// --- 1. scatter edges directly into over-allocated bucket regions ---
// Pass 1: int4 dst loads, LDS-atomic count, dst+rank kept in registers.
// Reserve: one global atomic per nonzero bucket (bcursor starts at 0).
// Pass 2: int4/float4 src/ew loads, write straight to reserved slots.
__global__ __launch_bounds__(256) void bucket_scatter_kernel(const int* __restrict__ src,
                                                             const int* __restrict__ dst,
                                                             const float* __restrict__ ew,
                                                             int* __restrict__ bcursor,
                                                             uint2* __restrict__ edgesB,
                                                             int E, int nbuck) {
    __shared__ int lh[MAXBUCK];
    __shared__ int lbase[MAXBUCK];
    const int tid = threadIdx.x;
    for (int i = tid; i < nbuck; i += 256) lh[i] = 0;
    __syncthreads();
    const int beg = blockIdx.x * SCHUNK;
    const bool vec = ((E & 3) == 0);
    int d[2][4], rk[2][4];
    #pragma unroll
    for (int j = 0; j < 2; j++) {
        int e = beg + j * 1024 + tid * 4;
        if (vec && e + 3 < E) {
            int4 dv = *(const int4*)(dst + e);
            d[j][0] = dv.x; d[j][1] = dv.y; d[j][2] = dv.z; d[j][3] = dv.w;
            #pragma unroll
            for (int k = 0; k < 4; k++) rk[j][k] = atomicAdd(&lh[d[j][k] >> 7], 1);
        } else {
            #pragma unroll
            for (int k = 0; k < 4; k++) {
                if (e + k < E) {
                    d[j][k] = dst[e + k];
                    rk[j][k] = atomicAdd(&lh[d[j][k] >> 7], 1);
                } else {
                    d[j][k] = -1;
                }
            }
        }
    }
    __syncthreads();
    for (int i = tid; i < nbuck; i += 256) {
        int c = lh[i];
        lbase[i] = c ? atomicAdd(&bcursor[i], c) : 0;
    }
    __syncthreads();
    #pragma unroll
    for (int j = 0; j < 2; j++) {
        int e = beg + j * 1024 + tid * 4;
        if (vec && e + 3 < E) {
            int4 sv = *(const int4*)(src + e);
            float4 wv = *(const float4*)(ew + e);
            int sa[4] = {sv.x, sv.y, sv.z, sv.w};
            float wa[4] = {wv.x, wv.y, wv.z, wv.w};
            #pragma unroll
            for (int k = 0; k < 4; k++) {
                int b = d[j][k] >> 7;
                int pos = lbase[b] + rk[j][k];
                if (pos < FCAP)
                    edgesB[(size_t)b * FCAP + pos] =
                        make_uint2((unsigned)sa[k] | ((unsigned)(d[j][k] & 127) << 17),
                                   __float_as_uint(wa[k]));
            }
        } else {
            #pragma unroll
            for (int k = 0; k < 4; k++) {
                if (d[j][k] >= 0) {
                    int b = d[j][k] >> 7;
                    int pos = lbase[b] + rk[j][k];
                    if (pos < FCAP)
                        edgesB[(size_t)b * FCAP + pos] =
                            make_uint2((unsigned)src[e + k] | ((unsigned)(d[j][k] & 127) << 17),
                                       __float_as_uint(ew[e + k]));
                }
            }
        }
    }
}

// --- 2. exclusive scan over buckets (counts come from bcursor) ---
__global__ __launch_bounds__(256) void bucket_scan_kernel(const int* __restrict__ bcursor,
                                                          int nbuck, int N,
                                                          int* __restrict__ outBase,
                                                          int* __restrict__ row_ptr) {
    __shared__ int sB[256];
    int tid = threadIdx.x;
    int v2[4];
    int s2 = 0;
    #pragma unroll
    for (int j = 0; j < 4; j++) {
        int idx = tid * 4 + j;
        int h = 0, nodes = 0;
        if (idx < nbuck) {
            h = bcursor[idx];
            h = h > FCAP ? FCAP : h;
            nodes = N - idx * NPB;
            nodes = nodes > NPB ? NPB : nodes;
            if (nodes < 0) nodes = 0;
        }
        v2[j] = h + nodes;
        s2 += v2[j];
    }
    sB[tid] = s2;
    __syncthreads();
    for (int off = 1; off < 256; off <<= 1) {
        int b = (tid >= off) ? sB[tid - off] : 0;
        __syncthreads();
        sB[tid] += b;
        __syncthreads();
    }
    int run2 = sB[tid] - s2;
    #pragma unroll
    for (int j = 0; j < 4; j++) {
        int idx = tid * 4 + j;
        if (idx < nbuck) outBase[idx] = run2;
        run2 += v2[j];
    }
    if (tid == 255) row_ptr[N] = run2;
}

// --- 3. per-bucket finalize ---
__global__ __launch_bounds__(256) void bucket_final_kernel(const uint2* __restrict__ edgesB,
                                                           const int* __restrict__ bcursor,
                                                           const int* __restrict__ outBase,
                                                           int* __restrict__ row_ptr,
                                                           float* __restrict__ dinv,
                                                           uint2* __restrict__ edges,
                                                           int N, int nbuck) {
    __shared__ uint2 eb[FCAP];
    __shared__ int cnts[NPB];
    __shared__ float wsum[NPB];
    __shared__ int starts[NPB];
    int b = blockIdx.x;
    int tid = threadIdx.x;
    size_t beg = (size_t)b * FCAP;
    int cnt = bcursor[b];
    if (cnt > FCAP) cnt = FCAP;
    int node0 = b * NPB;
    int nn = N - node0; if (nn > NPB) nn = NPB;
    for (int i = tid; i < nn; i += 256) { cnts[i] = 0; wsum[i] = 0.f; }
    for (int i = tid; i < cnt; i += 256) eb[i] = edgesB[beg + i];
    __syncthreads();
    for (int i = tid; i < cnt; i += 256) {
        int dl = eb[i].x >> 17;
        atomicAdd(&cnts[dl], 1);
        atomicAdd(&wsum[dl], __uint_as_float(eb[i].y));
    }
    __syncthreads();
    if (tid < 64) {
        int i0 = 2 * tid, i1 = 2 * tid + 1;
        int c0 = (i0 < nn) ? cnts[i0] + 1 : 0;
        int c1 = (i1 < nn) ? cnts[i1] + 1 : 0;
        int s = c0 + c1;
        int incl = s;
        #pragma unroll
        for (int off = 1; off < 64; off <<= 1) {
            int t = __shfl_up(incl, off);
            if (tid >= off) incl += t;
        }
        int excl = incl - s;
        int outB = outBase[b];
        if (i0 < nn) starts[i0] = outB + excl;
        if (i1 < nn) starts[i1] = outB + excl + c0;
    }
    __syncthreads();
    for (int i = tid; i < nn; i += 256) {
        int rp = starts[i];
        int node = node0 + i;
        row_ptr[node] = rp;
        dinv[node] = rsqrtf(wsum[i] + 1.0f);
        edges[rp] = make_uint2((unsigned)node, __float_as_uint(1.0f));
        cnts[i] = 1;
    }
    __syncthreads();
    for (int i = tid; i < cnt; i += 256) {
        int dl = eb[i].x >> 17;
        int r = atomicAdd(&cnts[dl], 1);
        edges[starts[dl] + r] = make_uint2(eb[i].x & 0x1FFFFu, eb[i].y);
    }
}

// W[K][NN] fp32 -> Bord fragment order: Bord[((t*KS+ks)*64+lane)*8+j]
//   = W[ks*32+(lane>>4)*8+j][t*16+(lane&15)]
template<int K, int NT>
__device__ inline void bord_fill(const float* __restrict__ W, _Float16* __restrict__ Bord,
                                 int i) {
    constexpr int NN = NT * 16;
    constexpr int KS = K / 32;
    int j = i & 7;
    int lane = (i >> 3) & 63;
    int ks = (i >> 9) % KS;
    int t = i / (KS * 512);
    int kk = ks * 32 + (lane >> 4) * 8 + j;
    int nnj = t * 16 + (lane & 15);
    Bord[i] = (_Float16)W[(size_t)kk * NN + nnj];
}

// fused: both weight reorders in one launch (sizes 32768 + 8192)
__global__ void convert_bord_both_kernel(const float* __restrict__ W1, _Float16* __restrict__ B1,
                                         const float* __restrict__ W2, _Float16* __restrict__ B2) {
    int i = blockIdx.x * blockDim.x + threadIdx.x;
    if (i < 32768) bord_fill<256, 8>(W1, B1, i);
    else if (i < 32768 + 8192) bord_fill<128, 4>(W2, B2, i - 32768);
}

// LDS-free MFMA GEMM, full K-strip register prefetch. One wave owns 16 rows.
// C[M,NN] = scale[m]*(A[M,K] @ B), B pre-shuffled to fragment order.
template<int K, int NT, int MINW, typename AT>
__global__ __launch_bounds__(256, MINW) void gemm_mfma_kernel(const AT* __restrict__ A,
                                                              const _Float16* __restrict__ Bord,
                                                              const float* __restrict__ scale,
                                                              _Float16* __restrict__ C, int M) {
    constexpr int NN = NT * 16;
    constexpr int KS = K / 32;
    const int wave_id = (blockIdx.x * blockDim.x + threadIdx.x) >> 6;
    const int lane = threadIdx.x & 63;
    const int quad = lane >> 4;
    const int nl = lane & 15;
    const int row_base = wave_id * 16;
    if (row_base >= M) return;
    const int m = min(row_base + nl, M - 1);

    // ---- prefetch the whole K-strip: all loads issued before first use ----
    float4 raw[KS][2];   // fp32 source path
    half8 afr[KS];       // fp16 source path
    if constexpr (sizeof(AT) == 4) {
        const float* ap = (const float*)A + (size_t)m * K + quad * 8;
        #pragma unroll
        for (int ks = 0; ks < KS; ks++) {
            raw[ks][0] = *(const float4*)(ap + ks * 32);
            raw[ks][1] = *(const float4*)(ap + ks * 32 + 4);
        }
    } else {
        const _Float16* ap = (const _Float16*)A + (size_t)m * K + quad * 8;
        #pragma unroll
        for (int ks = 0; ks < KS; ks++)
            afr[ks] = *(const half8*)(ap + ks * 32);
    }

    f32x4 acc[NT] = {};
    #pragma unroll
    for (int ks = 0; ks < KS; ks++) {
        half8 af;
        if constexpr (sizeof(AT) == 4) {
            af[0] = (_Float16)raw[ks][0].x; af[1] = (_Float16)raw[ks][0].y;
            af[2] = (_Float16)raw[ks][0].z; af[3] = (_Float16)raw[ks][0].w;
            af[4] = (_Float16)raw[ks][1].x; af[5] = (_Float16)raw[ks][1].y;
            af[6] = (_Float16)raw[ks][1].z; af[7] = (_Float16)raw[ks][1].w;
        } else {
            af = afr[ks];
        }
        #pragma unroll
        for (int t = 0; t < NT; t++) {
            half8 bf = *(const half8*)(Bord + ((size_t)(t * KS + ks) * 64 + lane) * 8);
            acc[t] = __builtin_amdgcn_mfma_f32_16x16x32_f16(af, bf, acc[t], 0, 0, 0);
        }
    }

    #pragma unroll
    for (int r = 0; r < 4; r++) {
        int grow = row_base + quad * 4 + r;
        if (grow < M) {
            float sc = scale[grow];
            #pragma unroll
            for (int t = 0; t < NT; t++)
                C[(size_t)grow * NN + t * 16 + nl] = (_Float16)(sc * acc[t][r]);
        }
    }
}

__device__ inline void accum8(float* acc, uint4 p, float v) {
    const __half2* q = (const __half2*)&p;
    #pragma unroll
    for (int k = 0; k < 4; k++) {
        float2 f = __half22float2(q[k]);
        acc[2 * k]     += v * f.x;
        acc[2 * k + 1] += v * f.y;
    }
}

// Layer-1 aggregation: out = relu(dinv[i]*sum(ew*h'[src]) + b1), fp16.
// R13: one node per 16-lane quarter, 8 edges in flight (fully unrolled,
// compile-time indices), __launch_bounds__(256,4) for VGPR headroom so the
// compiler actually keeps 8 gathers outstanding.
__global__ __launch_bounds__(256, 4) void agg1_kernel(const __half* __restrict__ h,
                                                      const int* __restrict__ row_ptr,
                                                      const uint2* __restrict__ edges,
                                                      const float* __restrict__ dinv,
                                                      const float* __restrict__ b1,
                                                      __half* __restrict__ out, int n) {
    const int wid = (blockIdx.x * blockDim.x + threadIdx.x) >> 6;
    const int lane = threadIdx.x & 63;
    const int q = lane >> 4;    // quarter = node slot
    const int l = lane & 15;    // feature lane (8 features each)
    const int node = wid * 4 + q;
    if (node >= n) return;
    const int beg = row_ptr[node], end = row_ptr[node + 1];
    float acc[8] = {};
    const __half* hb = h + l * 8;
    for (int e0 = beg; e0 < end; e0 += 8) {
        uint2 m[8];
        float v[8];
        uint4 p[8];
        #pragma unroll
        for (int k = 0; k < 8; k++) {
            int e = e0 + k;
            int ce = min(e, end - 1);
            m[k] = edges[ce];
            v[k] = (e < end) ? __uint_as_float(m[k].y) : 0.f;
        }
        #pragma unroll
        for (int k = 0; k < 8; k++)
            p[k] = *(const uint4*)(hb + (size_t)m[k].x * 128);
        #pragma unroll
        for (int k = 0; k < 8; k++)
            accum8(acc, p[k], v[k]);
    }
    const float di = dinv[node];
    const float4 b0 = *(const float4*)(b1 + l * 8);
    const float4 b1v = *(const float4*)(b1 + l * 8 + 4);
    float r[8] = {di * acc[0] + b0.x, di * acc[1] + b0.y, di * acc[2] + b0.z,
                  di * acc[3] + b0.w, di * acc[4] + b1v.x, di * acc[5] + b1v.y,
                  di * acc[6] + b1v.z, di * acc[7] + b1v.w};
    #pragma unroll
    for (int j = 0; j < 8; j++) r[j] = r[j] > 0.f ? r[j] : 0.f;
    __half2 o[4];
    #pragma unroll
    for (int k = 0; k < 4; k++) o[k] = __floats2half2_rn(r[2 * k], r[2 * k + 1]);
    *(uint4*)(out + (size_t)node * 128 + l * 8) = *(uint4*)o;
}

// Layer-2 aggregation + log_softmax.
// R13: one node per 8-lane octet, 8 edges in flight, VGPR headroom.
__global__ __launch_bounds__(256, 4) void agg2_kernel(const __half* __restrict__ h2,
                                                      const int* __restrict__ row_ptr,
                                                      const uint2* __restrict__ edges,
                                                      const float* __restrict__ dinv,
                                                      const float* __restrict__ b2,
                                                      float* __restrict__ out, int n) {
    const int wid = (blockIdx.x * blockDim.x + threadIdx.x) >> 6;
    const int lane = threadIdx.x & 63;
    const int o8 = lane >> 3;   // octet = node slot
    const int l = lane & 7;     // feature lane (8 features each)
    const int node = wid * 8 + o8;
    if (node >= n) return;
    const int beg = row_ptr[node], end = row_ptr[node + 1];
    float acc[8] = {};
    const __half* hb = h2 + l * 8;
    for (int e0 = beg; e0 < end; e0 += 8) {
        uint2 m[8];
        float v[8];
        uint4 p[8];
        #pragma unroll
        for (int k = 0; k < 8; k++) {
            int e = e0 + k;
            int ce = min(e, end - 1);
            m[k] = edges[ce];
            v[k] = (e < end) ? __uint_as_float(m[k].y) : 0.f;
        }
        #pragma unroll
        for (int k = 0; k < 8; k++)
            p[k] = *(const uint4*)(hb + (size_t)m[k].x * 64);
        #pragma unroll
        for (int k = 0; k < 8; k++)
            accum8(acc, p[k], v[k]);
    }
    const float di = dinv[node];
    const float4 b0 = *(const float4*)(b2 + l * 8);
    const float4 b1v = *(const float4*)(b2 + l * 8 + 4);
    acc[0] = di * acc[0] + b0.x;  acc[1] = di * acc[1] + b0.y;
    acc[2] = di * acc[2] + b0.z;  acc[3] = di * acc[3] + b0.w;
    acc[4] = di * acc[4] + b1v.x; acc[5] = di * acc[5] + b1v.y;
    acc[6] = di * acc[6] + b1v.z; acc[7] = di * acc[7] + b1v.w;
    float m = acc[0];
    #pragma unroll
    for (int j = 1; j < 8; j++) m = fmaxf(m, acc[j]);
    #pragma unroll
    for (int off = 1; off < 8; off <<= 1) m = fmaxf(m, __shfl_xor(m, off));
    float s = 0.f;
    #pragma unroll
    for (int j = 0; j < 8; j++) s += expf(acc[j] - m);
    #pragma unroll
    for (int off = 1; off < 8; off <<= 1) s += __shfl_xor(s, off);
    float ls = m + logf(s);
    float* op = out + (size_t)node * 64 + l * 8;
    *(float4*)(op)     = make_float4(acc[0] - ls, acc[1] - ls, acc[2] - ls, acc[3] - ls);
    *(float4*)(op + 4) = make_float4(acc[4] - ls, acc[5] - ls, acc[6] - ls, acc[7] - ls);
}

extern "C" void kernel_launch(void* const* d_in, const int* in_sizes, int n_in,
                              void* d_out, int out_size, void* d_ws, size_t ws_size,
                              hipStream_t stream) {
    const float* x  = (const float*)d_in[0];
    const int*   ei = (const int*)d_in[1];
    const float* ew = (const float*)d_in[2];
    const float* W1 = (const float*)d_in[3];
    const float* b1 = (const float*)d_in[4];
    const float* W2 = (const float*)d_in[5];
    const float* b2 = (const float*)d_in[6];
    float* out = (float*)d_out;

    const int N = in_sizes[0] / 256;
    const int E = in_sizes[1] / 2;
    const int Et = E + N;
    const int* src = ei;
    const int* dst = ei + E;
    const int nbuck = (N + NPB - 1) / NPB;

    char* w = (char*)d_ws;
    size_t off = 0;
    auto carve = [&](size_t bytes) {
        void* p = w + off;
        off = (off + bytes + 255) & ~(size_t)255;
        return p;
    };
    int*      bcursor = (int*)  carve((size_t)MAXBUCK * 4);
    int*      outBase = (int*)  carve((size_t)MAXBUCK * 4);
    int*      row_ptr = (int*)  carve((size_t)(N + 1) * 4);
    float*    dinv    = (float*)carve((size_t)N * 4);
    uint2*    edgesB  = (uint2*)carve((size_t)MAXBUCK * FCAP * 8);
    uint2*    edges   = (uint2*)carve((size_t)Et * 8);
    _Float16* bord1   = (_Float16*)carve((size_t)256 * 128 * 2);
    _Float16* bord2   = (_Float16*)carve((size_t)128 * 64 * 2);
    _Float16* bufA    = (_Float16*)carve((size_t)N * 128 * 2);  // h'; later h2' (aliased)
    _Float16* bufB    = (_Float16*)carve((size_t)N * 128 * 2);  // h1
    _Float16* bufC    = bufA;

    // 1. bucket-sort CSR build (no hist pass: scatter-first into FCAP regions)
    hipMemsetAsync(bcursor, 0, (size_t)nbuck * 4, stream);
    const int scat_blocks = (E + SCHUNK - 1) / SCHUNK;
    bucket_scatter_kernel<<<scat_blocks, 256, 0, stream>>>(src, dst, ew, bcursor, edgesB, E, nbuck);
    bucket_scan_kernel<<<1, 256, 0, stream>>>(bcursor, nbuck, N, outBase, row_ptr);
    bucket_final_kernel<<<nbuck, 256, 0, stream>>>(edgesB, bcursor, outBase, row_ptr, dinv,
                                                   edges, N, nbuck);

    // weight reorders (tiny, fused)
    convert_bord_both_kernel<<<(32768 + 8192 + 255) / 256, 256, 0, stream>>>(W1, bord1, W2, bord2);

    // 2. Layer 1: h' = dinv * (x @ W1), h1 = relu(dinv*agg(h')+b1)
    const int waves = (N + 15) / 16;            // 16 rows per wave
    const int gemm_blocks = (waves + 3) / 4;    // 4 waves per block
    gemm_mfma_kernel<256, 8, 4, float><<<gemm_blocks, 256, 0, stream>>>(x, bord1, dinv, bufA, N);
    agg1_kernel<<<(N + 15) / 16, 256, 0, stream>>>((const __half*)bufA, row_ptr, edges, dinv, b1,
                                                   (__half*)bufB, N);

    // 3. Layer 2: h2' = dinv * (h1 @ W2), out = log_softmax(dinv*agg(h2')+b2)
    gemm_mfma_kernel<128, 4, 6, _Float16><<<gemm_blocks, 256, 0, stream>>>(bufB, bord2, dinv,
                                                                           bufC, N);
    agg2_kernel<<<(N + 31) / 32, 256, 0, stream>>>((const __half*)bufC, row_ptr, edges, dinv, b2,
                                                   out, N);
}